// Round 2
// baseline (2416.489 us; speedup 1.0000x reference)
//
#include <hip/hip_runtime.h>
#include <hip/hip_bf16.h>
#include <math.h>

typedef __hip_bfloat16 bf16;
typedef __hip_bfloat162 bf162;

static __device__ __forceinline__ float b2f(bf16 v){ return __bfloat162float(v); }
static __device__ __forceinline__ bf16  f2b(float v){ return __float2bfloat16(v); }
static __device__ __forceinline__ float ldf(float v){ return v; }
static __device__ __forceinline__ float ldf(bf16 v){ return __bfloat162float(v); }
static __device__ __forceinline__ float sigm(float v){ return 1.f/(1.f+__expf(-v)); }

static __device__ __forceinline__ void load4(const float* p, float v[4]){
    float4 t = *(const float4*)p;
    v[0]=t.x; v[1]=t.y; v[2]=t.z; v[3]=t.w;
}
static __device__ __forceinline__ void load4(const bf16* p, float v[4]){
    bf162 a = ((const bf162*)p)[0], b = ((const bf162*)p)[1];
    v[0]=b2f(a.x); v[1]=b2f(a.y); v[2]=b2f(b.x); v[3]=b2f(b.y);
}
static __device__ __forceinline__ void store4(float* p, const float v[4]){
    float4 t; t.x=v[0]; t.y=v[1]; t.z=v[2]; t.w=v[3];
    *(float4*)p = t;
}
static __device__ __forceinline__ void store4(bf16* p, const float v[4]){
    bf162 a,b; a.x=f2b(v[0]); a.y=f2b(v[1]); b.x=f2b(v[2]); b.y=f2b(v[3]);
    ((bf162*)p)[0]=a; ((bf162*)p)[1]=b;
}

#define P_IMG 4096   // 64*64

// ---------------- workspace layout (bytes) ----------------
// x_att bf16 (32,256,4096)                    [0, 67108864)
// big   bf16: PA-hidden / MLP hidden          [67108864, 201326592)
//   misc (dead before MLP1) lives in the second half of big:
namespace {
constexpr long long XATT_OFF = 0;
constexpr long long BIG_OFF  = 67108864;
constexpr long long MISC     = 134217728;
constexpr long long XM_OFF   = MISC;                 // f32 (2048,484)
constexpr long long MSUM_OFF = MISC + 3964928;       // f32 (2048,484)
constexpr long long SH_OFF   = MISC + 7929856;       // f32 (2048,946)
constexpr long long SH2_OFF  = MISC + 15679488;      // f32 (2048,946)
constexpr long long X4P_OFF  = MISC + 23429120;      // f32 (32,64,1024)
constexpr long long IDX1_OFF = MISC + 31817728;      // i32 (32,64,1024)
constexpr long long XP_OFF   = MISC + 40206336;      // f32 (32,64,256)
constexpr long long IDX2_OFF = MISC + 42303488;      // i32
constexpr long long HBUF_OFF = MISC + 44400640;      // f32 (32,64,256)
constexpr long long A1_OFF   = MISC + 46497792;
constexpr long long A2_OFF   = MISC + 48594944;
constexpr long long A1S_OFF  = MISC + 50692096;      // f32 (32,32,256)
constexpr long long A2S_OFF  = MISC + 51740672;
constexpr long long AGG_OFF  = MISC + 52789248;      // f32 (32,2,256)
constexpr long long SIG_OFF  = MISC + 52854784;
constexpr long long ATTN_OFF = MISC + 52920320;      // f32 (32,64,256)
constexpr long long H2_OFF   = MISC + 55017472;
constexpr long long XG_OFF   = MISC + 57114624;      // f32 (32,64,1024)
constexpr long long P33_OFF  = 201326592;            // f32 (32,64,4096): LA conv out, then maxpool3 out
constexpr long long STATS_OFF= 234881024;            // raw sums (1920 f) + finalized float2 (960)
constexpr long long WS_NEED  = 234897408;
}

__global__ __launch_bounds__(256) void zero_out_k(float* __restrict__ o, int n){
    int i = blockIdx.x*256 + threadIdx.x;
    if (i < n) o[i] = 0.f;
}

// ============ generic 1x1 conv over (B,C,4096): out[b,o,p] = sum_c f(in[b,c,p])*W[o,c] ============
// 4 px * 8 outs per thread. grid (4, Cout/8, 32), block 256.
// instats != null -> input transform relu((v-mean)*inv).  epi: 0 plain, 1 aux*sigmoid(acc), 2 aux+acc.
template<typename TIN, typename TOUT>
__global__ __launch_bounds__(256) void conv1x1_k(
    const TIN* __restrict__ in, int inCtot, int inOff,
    const float2* __restrict__ instats,
    const float* __restrict__ Wt, int Cin,
    TOUT* __restrict__ out, int outCtot, int outOff,
    const float* __restrict__ aux, int auxCtot, int auxOff, int epi)
{
    __shared__ float wsf[8*512];
    const int tid = threadIdx.x;
    const int og = blockIdx.y;
    const int b  = blockIdx.z;
    for (int t = tid; t < 8*Cin; t += 256){
        int c = t >> 3, j = t & 7;
        wsf[t] = Wt[(og*8 + j)*Cin + c];
    }
    __syncthreads();
    const int p0 = (blockIdx.x*256 + tid)*4;
    const TIN* ib = in + ((long)b*inCtot + inOff)*P_IMG + p0;
    float acc[8][4];
    #pragma unroll
    for (int j=0;j<8;j++){
        #pragma unroll
        for (int k=0;k<4;k++) acc[j][k]=0.f;
    }
    for (int c=0;c<Cin;c++){
        float v[4];
        load4(ib + (long)c*P_IMG, v);
        if (instats){
            float2 s = instats[c];
            #pragma unroll
            for (int k=0;k<4;k++){ float t2=(v[k]-s.x)*s.y; v[k] = t2>0.f ? t2 : 0.f; }
        }
        #pragma unroll
        for (int j=0;j<8;j++){
            float w = wsf[c*8 + j];
            #pragma unroll
            for (int k=0;k<4;k++) acc[j][k] = fmaf(v[k], w, acc[j][k]);
        }
    }
    #pragma unroll
    for (int j=0;j<8;j++){
        int o = og*8 + j;
        float r[4] = {acc[j][0],acc[j][1],acc[j][2],acc[j][3]};
        if (epi==1){
            float av[4];
            load4(aux + ((long)b*auxCtot + auxOff + o)*P_IMG + p0, av);
            #pragma unroll
            for (int k=0;k<4;k++) r[k] = av[k] * sigm(r[k]);
        } else if (epi==2){
            float av[4];
            load4(aux + ((long)b*auxCtot + auxOff + o)*P_IMG + p0, av);
            #pragma unroll
            for (int k=0;k<4;k++) r[k] = av[k] + r[k];
        }
        store4(out + ((long)b*outCtot + outOff + o)*P_IMG + p0, r);
    }
}

// ============ BN batch-stats: per-channel sum / sumsq over (B, Pn) ============
template<typename T>
__global__ __launch_bounds__(256) void bnstats_k(const T* __restrict__ in, int Ctot, int cOff, int Pn,
                                                 float* __restrict__ sums)
{
    const int c = blockIdx.x;
    float s=0.f, s2=0.f;
    for (int b=0;b<32;b++){
        const T* q = in + ((long)b*Ctot + cOff + c)*Pn;
        for (int p = blockIdx.y*256 + threadIdx.x; p < Pn; p += gridDim.y*256){
            float v = ldf(q[p]);
            s += v; s2 = fmaf(v,v,s2);
        }
    }
    __shared__ float r1[256], r2[256];
    r1[threadIdx.x]=s; r2[threadIdx.x]=s2;
    __syncthreads();
    for (int k=128;k>0;k>>=1){
        if (threadIdx.x<k){ r1[threadIdx.x]+=r1[threadIdx.x+k]; r2[threadIdx.x]+=r2[threadIdx.x+k]; }
        __syncthreads();
    }
    if (threadIdx.x==0){ atomicAdd(&sums[2*c], r1[0]); atomicAdd(&sums[2*c+1], r2[0]); }
}

__global__ __launch_bounds__(256) void bnfin_k(const float* __restrict__ sums, float2* __restrict__ minv,
                                               int C, float invN)
{
    int c = blockIdx.x*256 + threadIdx.x;
    if (c < C){
        float m = sums[2*c]*invN;
        float var = sums[2*c+1]*invN - m*m;
        minv[c] = make_float2(m, 1.f/sqrtf(var + 1e-5f));
    }
}

// ============ LA: 3x3 conv, 64->64, pad 1, on x channels [64,128) ============
__global__ __launch_bounds__(256) void la_conv3_k(const float* __restrict__ x, const float* __restrict__ w,
                                                  float* __restrict__ y)
{
    __shared__ float wsf[64*9*8];
    const int tid = threadIdx.x, og = blockIdx.y, b = blockIdx.z;
    for (int t = tid; t < 64*9*8; t += 256){
        int j = t & 7, ct = t >> 3;
        int c = ct / 9, tap = ct - 9*c;
        wsf[t] = w[((og*8 + j)*64 + c)*9 + tap];
    }
    __syncthreads();
    const int p = blockIdx.x*256 + tid;
    const int h = p >> 6, wc = p & 63;
    float acc[8];
    #pragma unroll
    for (int j=0;j<8;j++) acc[j]=0.f;
    for (int c=0;c<64;c++){
        const float* xb = x + ((long)b*256 + 64 + c)*P_IMG;
        #pragma unroll
        for (int kh=0;kh<3;kh++){
            int hh = h + kh - 1;
            if ((unsigned)hh >= 64u) continue;
            #pragma unroll
            for (int kw=0;kw<3;kw++){
                int ww = wc + kw - 1;
                if ((unsigned)ww >= 64u) continue;
                float v = xb[hh*64 + ww];
                const float* wr = &wsf[(c*9 + kh*3 + kw)*8];
                #pragma unroll
                for (int j=0;j<8;j++) acc[j] = fmaf(v, wr[j], acc[j]);
            }
        }
    }
    #pragma unroll
    for (int j=0;j<8;j++) y[((long)b*64 + og*8 + j)*P_IMG + p] = acc[j];
}

__global__ __launch_bounds__(256) void la_post_k(const float* __restrict__ y, const float2* __restrict__ minv,
                                                 bf16* __restrict__ xatt)
{
    int i = blockIdx.x*256 + threadIdx.x;   // < 8388608
    int b = i >> 18, o = (i >> 12) & 63, p = i & 4095;
    float2 st = minv[o];
    float v = (y[i] - st.x)*st.y;
    v = fmaxf(v, 0.f);
    xatt[((long)b*256 + 64 + o)*P_IMG + p] = f2b(v);
}

// ============ MRA ============
__global__ __launch_bounds__(256) void mp3_k(const float* __restrict__ x, float* __restrict__ mp){
    int i = blockIdx.x*256 + threadIdx.x;   // < 8388608, layout (b,c,64,64) == (bc,4096)
    int b = i >> 18, c = (i >> 12) & 63, p = i & 4095;
    int h = p >> 6, wc = p & 63;
    const float* xb = x + ((long)b*256 + 128 + c)*P_IMG;
    float m = -3.4e38f;
    #pragma unroll
    for (int dh=-1; dh<=1; dh++){
        int hh = h+dh; if ((unsigned)hh>=64u) continue;
        #pragma unroll
        for (int dw=-1; dw<=1; dw++){
            int ww = wc+dw; if ((unsigned)ww>=64u) continue;
            m = fmaxf(m, xb[hh*64+ww]);
        }
    }
    mp[i] = m;
}

__global__ __launch_bounds__(256) void blur_k(const float* __restrict__ mp, float* __restrict__ xm){
    int idx = blockIdx.x*256 + threadIdx.x;   // < 991232 = 2048*484
    int oj = idx % 22; int t = idx / 22; int oi = t % 22; int bc = t / 22;
    const float* mb = mp + (long)bc * P_IMG;
    const float fw[4] = {1.f,3.f,3.f,1.f};
    float s = 0.f;
    #pragma unroll
    for (int u=0;u<4;u++){
        int r = 3*oi - 1 + u;
        r = r < 0 ? -r : (r > 63 ? 126 - r : r);   // np 'reflect'
        float rs = 0.f;
        #pragma unroll
        for (int v=0; v<4; v++){
            int q = 3*oj - 1 + v;
            q = q < 0 ? -q : (q > 63 ? 126 - q : q);
            rs = fmaf(fw[v], mb[r*64+q], rs);
        }
        s = fmaf(fw[u], rs, s);
    }
    xm[idx] = s * (1.f/64.f);
}

__global__ __launch_bounds__(256) void strips_k(const float* __restrict__ xm, const float* __restrict__ wh1,
                                                const float* __restrict__ wv1, float* __restrict__ msum)
{
    int idx = blockIdx.x*256 + threadIdx.x;   // < 991232
    int j = idx % 22; int t = idx / 22; int i = t % 22; int bc = t / 22; int c = bc & 63;
    const float* xb = xm + (long)bc*484;
    float s = 0.f;
    #pragma unroll
    for (int u=0;u<11;u++){               // 11x3, pad (5,1)
        int ii = i + u - 5; if ((unsigned)ii >= 22u) continue;
        #pragma unroll
        for (int v=0;v<3;v++){
            int jj = j + v - 1; if ((unsigned)jj >= 22u) continue;
            s = fmaf(wh1[c*33 + u*3 + v], xb[ii*22+jj], s);
        }
    }
    #pragma unroll
    for (int u=0;u<3;u++){                // 3x11, pad (1,5)
        int ii = i + u - 1; if ((unsigned)ii >= 22u) continue;
        #pragma unroll
        for (int v=0;v<11;v++){
            int jj = j + v - 5; if ((unsigned)jj >= 22u) continue;
            s = fmaf(wv1[c*33 + u*11 + v], xb[ii*22+jj], s);
        }
    }
    msum[idx] = s;
}

// h_tf(xm): (22,43); X[i,j] = xm[f/44, f%44] if f%44<22 else 0, f=i*43+j
__global__ __launch_bounds__(256) void shearh_k(const float* __restrict__ xm, float* __restrict__ sh){
    int idx = blockIdx.x*256 + threadIdx.x;   // < 1937408 = 2048*946
    int j = idx % 43; int t = idx / 43; int i = t % 22; int bc = t / 22;
    int f = i*43 + j; int r = f / 44; int q = f - 44*r;
    sh[idx] = (q < 22) ? xm[(long)bc*484 + r*22 + q] : 0.f;
}

__global__ __launch_bounds__(256) void shconvh_k(const float* __restrict__ sh, const float* __restrict__ w2,
                                                 float* __restrict__ sh2)
{
    int idx = blockIdx.x*256 + threadIdx.x;   // < 1937408
    int j = idx % 43; int t = idx / 43; int i = t % 22; int bc = t / 22; int c = bc & 63;
    const float* sb = sh + (long)bc*946;
    float s = 0.f;
    #pragma unroll
    for (int u=0;u<11;u++){
        int ii = i + u - 5; if ((unsigned)ii >= 22u) continue;
        #pragma unroll
        for (int v=0;v<3;v++){
            int jj = j + v - 1; if ((unsigned)jj >= 43u) continue;
            s = fmaf(w2[c*33 + u*3 + v], sb[ii*43+jj], s);
        }
    }
    sh2[idx] = s;
}

// inv_h_tf: out[i,j] = sh2[f/43, f%43], f = i*44+j
__global__ __launch_bounds__(256) void shaddh_k(const float* __restrict__ sh2, float* __restrict__ msum){
    int idx = blockIdx.x*256 + threadIdx.x;   // < 991232
    int j = idx % 22; int t = idx / 22; int i = t % 22; int bc = t / 22;
    int f = i*44 + j; int r = f / 43; int q = f - 43*r;
    msum[idx] += sh2[(long)bc*946 + r*43 + q];
}

// v_tf(xm): (43,22); V[i,j] = xm[g%44, g/44] if g%44<22 else 0, g=j*43+i
__global__ __launch_bounds__(256) void shearv_k(const float* __restrict__ xm, float* __restrict__ sv){
    int idx = blockIdx.x*256 + threadIdx.x;   // < 1937408, layout (bc,43,22)
    int j = idx % 22; int t = idx / 22; int i = t % 43; int bc = t / 43;
    int g = j*43 + i; int r = g / 44; int q = g - 44*r;
    sv[idx] = (q < 22) ? xm[(long)bc*484 + q*22 + r] : 0.f;
}

__global__ __launch_bounds__(256) void shconvv_k(const float* __restrict__ sv, const float* __restrict__ wv2,
                                                 float* __restrict__ sv2)
{
    int idx = blockIdx.x*256 + threadIdx.x;   // < 1937408
    int j = idx % 22; int t = idx / 22; int i = t % 43; int bc = t / 43; int c = bc & 63;
    const float* sb = sv + (long)bc*946;
    float s = 0.f;
    #pragma unroll
    for (int u=0;u<3;u++){                // 3x11, pad (1,5)
        int ii = i + u - 1; if ((unsigned)ii >= 43u) continue;
        #pragma unroll
        for (int v=0;v<11;v++){
            int jj = j + v - 5; if ((unsigned)jj >= 22u) continue;
            s = fmaf(wv2[c*33 + u*11 + v], sb[ii*22+jj], s);
        }
    }
    sv2[idx] = s;
}

// inv_v_tf: R[y,x] = sv2[g%43, g/43], g = x*44+y
__global__ __launch_bounds__(256) void shaddv_k(const float* __restrict__ sv2, float* __restrict__ msum){
    int idx = blockIdx.x*256 + threadIdx.x;   // < 991232, msum layout (bc, y, x)
    int xcol = idx % 22; int t = idx / 22; int y = t % 22; int bc = t / 22;
    int g = xcol*44 + y; int r = g / 43; int q = g - 43*r;
    msum[idx] += sv2[(long)bc*946 + q*22 + r];
}

__global__ __launch_bounds__(256) void mra_gate_k(const float* __restrict__ x, const float* __restrict__ msum,
                                                  const float2* __restrict__ minv, bf16* __restrict__ xatt)
{
    int i = blockIdx.x*256 + threadIdx.x;   // < 8388608
    int b = i >> 18, c = (i >> 12) & 63, p = i & 4095;
    int h = p >> 6, wcol = p & 63;
    int ri = (h*22) >> 6, ci = (wcol*22) >> 6;   // torch nearest rule
    float g = msum[((long)b*64 + c)*484 + ri*22 + ci];
    float2 st = minv[c];
    g = sigm((g - st.x)*st.y);
    long xi = ((long)b*256 + 128 + c)*P_IMG + p;
    xatt[xi] = f2b(x[xi] * g);
}

// ============ GA (D_GA stage 2) ============
__global__ __launch_bounds__(256) void pool1_k(const float* __restrict__ x, float* __restrict__ x4p,
                                               int* __restrict__ idx1)
{
    int i = blockIdx.x*256 + threadIdx.x;   // < 2097152, out (b,c,32,32)
    int b = i >> 16, c = (i >> 10) & 63, s = i & 1023;
    int y = s >> 5, xc = s & 31;
    const float* xb = x + ((long)b*256 + 192 + c)*P_IMG;
    float v00 = xb[(2*y)*64 + 2*xc];
    float v01 = xb[(2*y)*64 + 2*xc + 1];
    float v10 = xb[(2*y+1)*64 + 2*xc];
    float v11 = xb[(2*y+1)*64 + 2*xc + 1];
    float best = v00; int bi = 0;
    if (v01 > best){ best = v01; bi = 1; }
    if (v10 > best){ best = v10; bi = 2; }
    if (v11 > best){ best = v11; bi = 3; }
    x4p[i] = best; idx1[i] = bi;
}

__global__ __launch_bounds__(256) void pool2_k(const float* __restrict__ x4p, float* __restrict__ xp,
                                               int* __restrict__ idx2)
{
    int i = blockIdx.x*256 + threadIdx.x;   // < 524288, out (b,c,16,16)
    int b = i >> 14, c = (i >> 8) & 63, s = i & 255;
    int y = s >> 4, xc = s & 15;
    const float* xb = x4p + ((long)b*64 + c)*1024;
    float v00 = xb[(2*y)*32 + 2*xc];
    float v01 = xb[(2*y)*32 + 2*xc + 1];
    float v10 = xb[(2*y+1)*32 + 2*xc];
    float v11 = xb[(2*y+1)*32 + 2*xc + 1];
    float best = v00; int bi = 0;
    if (v01 > best){ best = v01; bi = 1; }
    if (v10 > best){ best = v10; bi = 2; }
    if (v11 > best){ best = v11; bi = 3; }
    xp[i] = best; idx2[i] = bi;
}

// 1x1 conv on (B,64,256) fp32, Cin=64, Cout in {32,64}; optional element-wise mul on input; +bias; opt relu
__global__ __launch_bounds__(256) void ga_proj_k(const float* __restrict__ in, const float* __restrict__ mul,
                                                 const float* __restrict__ w, const float* __restrict__ bias,
                                                 float* __restrict__ out, int Cout, int relu)
{
    int s = threadIdx.x, og = blockIdx.x, b = blockIdx.y;
    float acc[8];
    #pragma unroll
    for (int j=0;j<8;j++) acc[j]=0.f;
    for (int c=0;c<64;c++){
        float v = in[((long)b*64 + c)*256 + s];
        if (mul) v *= mul[((long)b*64 + c)*256 + s];
        #pragma unroll
        for (int j=0;j<8;j++) acc[j] = fmaf(v, w[(og*8 + j)*64 + c], acc[j]);
    }
    #pragma unroll
    for (int j=0;j<8;j++){
        int o = og*8 + j;
        float val = acc[j] + bias[o];
        if (relu) val = fmaxf(val, 0.f);
        out[((long)b*Cout + o)*256 + s] = val;
    }
}

__global__ __launch_bounds__(256) void ga_dw5_k(const float* __restrict__ h, const float* __restrict__ w,
                                                const float* __restrict__ bias, float* __restrict__ a1)
{
    int i = blockIdx.x*256 + threadIdx.x;   // < 524288
    int b = i >> 14, c = (i >> 8) & 63, s = i & 255;
    int y = s >> 4, x = s & 15;
    const float* hb = h + ((long)b*64 + c)*256;
    float acc = bias[c];
    #pragma unroll
    for (int u=0;u<5;u++){
        int yy = y + u - 2; if ((unsigned)yy >= 16u) continue;
        #pragma unroll
        for (int v=0;v<5;v++){
            int xx = x + v - 2; if ((unsigned)xx >= 16u) continue;
            acc = fmaf(w[c*25 + u*5 + v], hb[yy*16 + xx], acc);
        }
    }
    a1[i] = acc;
}

__global__ __launch_bounds__(256) void ga_dw7_k(const float* __restrict__ a1, const float* __restrict__ w,
                                                const float* __restrict__ bias, float* __restrict__ a2)
{
    int i = blockIdx.x*256 + threadIdx.x;   // < 524288, 7x7 dil3 pad9
    int b = i >> 14, c = (i >> 8) & 63, s = i & 255;
    int y = s >> 4, x = s & 15;
    const float* ab = a1 + ((long)b*64 + c)*256;
    float acc = bias[c];
    #pragma unroll
    for (int u=0;u<7;u++){
        int yy = y + 3*(u-3); if ((unsigned)yy >= 16u) continue;
        #pragma unroll
        for (int v=0;v<7;v++){
            int xx = x + 3*(v-3); if ((unsigned)xx >= 16u) continue;
            acc = fmaf(w[c*49 + u*7 + v], ab[yy*16 + xx], acc);
        }
    }
    a2[i] = acc;
}

__global__ __launch_bounds__(256) void ga_agg_k(const float* __restrict__ a1s, const float* __restrict__ a2s,
                                                float* __restrict__ agg)
{
    int i = blockIdx.x*256 + threadIdx.x;   // < 8192
    int b = i >> 8, s = i & 255;
    float sum = 0.f, mx = -3.4e38f;
    for (int c=0;c<32;c++){
        float v = a1s[((long)b*32 + c)*256 + s];
        sum += v; mx = fmaxf(mx, v);
    }
    for (int c=0;c<32;c++){
        float v = a2s[((long)b*32 + c)*256 + s];
        sum += v; mx = fmaxf(mx, v);
    }
    agg[((long)b*2 + 0)*256 + s] = sum * (1.f/64.f);
    agg[((long)b*2 + 1)*256 + s] = mx;
}

__global__ __launch_bounds__(256) void ga_sq_k(const float* __restrict__ agg, const float* __restrict__ w,
                                               const float* __restrict__ bias, float* __restrict__ sig)
{
    int i = blockIdx.x*256 + threadIdx.x;   // < 16384
    int b = i >> 9, o = (i >> 8) & 1, s = i & 255;
    int y = s >> 4, x = s & 15;
    float acc = bias[o];
    for (int ic=0; ic<2; ic++){
        const float* ab = agg + ((long)b*2 + ic)*256;
        #pragma unroll
        for (int u=0;u<7;u++){
            int yy = y + u - 3; if ((unsigned)yy >= 16u) continue;
            #pragma unroll
            for (int v=0;v<7;v++){
                int xx = x + v - 3; if ((unsigned)xx >= 16u) continue;
                acc = fmaf(w[((o*2 + ic)*7 + u)*7 + v], ab[yy*16 + xx], acc);
            }
        }
    }
    sig[i] = sigm(acc);
}

__global__ __launch_bounds__(256) void ga_attn_k(const float* __restrict__ a1s, const float* __restrict__ a2s,
                                                 const float* __restrict__ sig, const float* __restrict__ w,
                                                 const float* __restrict__ bias, float* __restrict__ attn)
{
    int s = threadIdx.x, og = blockIdx.x, b = blockIdx.y;
    float s0 = sig[((long)b*2 + 0)*256 + s];
    float s1 = sig[((long)b*2 + 1)*256 + s];
    float acc[8];
    #pragma unroll
    for (int j=0;j<8;j++) acc[j]=0.f;
    for (int c=0;c<32;c++){
        float v = a1s[((long)b*32 + c)*256 + s]*s0 + a2s[((long)b*32 + c)*256 + s]*s1;
        #pragma unroll
        for (int j=0;j<8;j++) acc[j] = fmaf(v, w[(og*8 + j)*32 + c], acc[j]);
    }
    #pragma unroll
    for (int j=0;j<8;j++){
        int o = og*8 + j;
        attn[((long)b*64 + o)*256 + s] = acc[j] + bias[o];
    }
}

__global__ __launch_bounds__(256) void ga_unpool1_k(const float* __restrict__ h2, const int* __restrict__ idx2,
                                                    float* __restrict__ xg)
{
    int i = blockIdx.x*256 + threadIdx.x;   // < 2097152, out (b,c,32,32)
    int b = i >> 16, c = (i >> 10) & 63, s = i & 1023;
    int Y = s >> 5, X = s & 31;
    int slot = ((Y & 1) << 1) | (X & 1);
    long pi = ((long)b*64 + c)*256 + (Y >> 1)*16 + (X >> 1);
    xg[i] = (idx2[pi] == slot) ? h2[pi] : 0.f;
}

__global__ __launch_bounds__(256) void ga_out_k(const float* __restrict__ xg, const int* __restrict__ idx1,
                                                const float2* __restrict__ minv, bf16* __restrict__ xatt)
{
    int i = blockIdx.x*256 + threadIdx.x;   // < 8388608
    int b = i >> 18, c = (i >> 12) & 63, p = i & 4095;
    int hh = p >> 6, ww = p & 63;
    int slot = ((hh & 1) << 1) | (ww & 1);
    long pi = ((long)b*64 + c)*1024 + (hh >> 1)*32 + (ww >> 1);
    float v = 0.f;
    if (idx1[pi] == slot){
        float2 st = minv[c];
        v = (xg[pi] - st.x)*st.y;
    }
    xatt[((long)b*256 + 192 + c)*P_IMG + p] = f2b(v);
}

// ============================================================================
extern "C" void kernel_launch(void* const* d_in, const int* in_sizes, int n_in,
                              void* d_out, int out_size, void* d_ws, size_t ws_size,
                              hipStream_t stream)
{
    const float* x      = (const float*)d_in[0];
    const float* pa_w1  = (const float*)d_in[1];
    const float* pa_w2  = (const float*)d_in[2];
    const float* la_w   = (const float*)d_in[3];
    const float* mra_h1 = (const float*)d_in[4];
    const float* mra_v1 = (const float*)d_in[5];
    const float* mra_h2 = (const float*)d_in[6];
    const float* mra_v2 = (const float*)d_in[7];
    const float* g_p1w  = (const float*)d_in[8];
    const float* g_p1b  = (const float*)d_in[9];
    const float* g_c0w  = (const float*)d_in[10];
    const float* g_c0b  = (const float*)d_in[11];
    const float* g_spw  = (const float*)d_in[12];
    const float* g_spb  = (const float*)d_in[13];
    const float* g_c1w  = (const float*)d_in[14];
    const float* g_c1b  = (const float*)d_in[15];
    const float* g_c2w  = (const float*)d_in[16];
    const float* g_c2b  = (const float*)d_in[17];
    const float* g_cw   = (const float*)d_in[18];
    const float* g_cb   = (const float*)d_in[19];
    const float* g_sqw  = (const float*)d_in[20];
    const float* g_sqb  = (const float*)d_in[21];
    const float* g_p2w  = (const float*)d_in[22];
    const float* g_p2b  = (const float*)d_in[23];
    const float* mlp_w1 = (const float*)d_in[24];
    const float* mlp_w2 = (const float*)d_in[25];
    float* outp = (float*)d_out;
    char* ws = (char*)d_ws;

    if (ws_size < (size_t)WS_NEED){
        zero_out_k<<<(out_size + 255)/256, 256, 0, stream>>>(outp, out_size);
        return;
    }

    bf16*  xatt = (bf16*)(ws + XATT_OFF);
    bf16*  tbuf = (bf16*)(ws + BIG_OFF);   // PA-hidden, later MLP-hidden
    float* xm   = (float*)(ws + XM_OFF);
    float* msum = (float*)(ws + MSUM_OFF);
    float* sh   = (float*)(ws + SH_OFF);
    float* sh2  = (float*)(ws + SH2_OFF);
    float* x4p  = (float*)(ws + X4P_OFF);
    int*   idx1 = (int*)(ws + IDX1_OFF);
    float* xp   = (float*)(ws + XP_OFF);
    int*   idx2 = (int*)(ws + IDX2_OFF);
    float* hbuf = (float*)(ws + HBUF_OFF);
    float* a1   = (float*)(ws + A1_OFF);
    float* a2   = (float*)(ws + A2_OFF);
    float* a1s  = (float*)(ws + A1S_OFF);
    float* a2s  = (float*)(ws + A2S_OFF);
    float* agg  = (float*)(ws + AGG_OFF);
    float* sig  = (float*)(ws + SIG_OFF);
    float* attn = (float*)(ws + ATTN_OFF);
    float* h2   = (float*)(ws + H2_OFF);
    float* xg   = (float*)(ws + XG_OFF);
    float* p33  = (float*)(ws + P33_OFF);
    float* raw  = (float*)(ws + STATS_OFF);
    float*  raw_pa  = raw;
    float*  raw_la  = raw + 512;
    float*  raw_mra = raw + 640;
    float*  raw_ga  = raw + 768;
    float*  raw_mlp = raw + 896;
    float2* mv_pa   = (float2*)(raw + 1920);
    float2* mv_la   = mv_pa + 256;
    float2* mv_mra  = mv_la + 64;
    float2* mv_ga   = mv_mra + 64;
    float2* mv_mlp  = mv_ga + 64;

    hipMemsetAsync(raw, 0, 1920*sizeof(float), stream);

    // ---- PA: x1 * sigmoid(conv2(relu(bn(conv1(x1))))) -> xatt[0:64) ----
    conv1x1_k<float,bf16><<<dim3(4,32,32),256,0,stream>>>(x,256,0, nullptr, pa_w1,64, tbuf,256,0, nullptr,0,0,0);
    bnstats_k<bf16><<<dim3(256,16),256,0,stream>>>(tbuf,256,0,4096, raw_pa);
    bnfin_k<<<1,256,0,stream>>>(raw_pa, mv_pa, 256, 1.f/131072.f);
    conv1x1_k<bf16,bf16><<<dim3(4,8,32),256,0,stream>>>(tbuf,256,0, mv_pa, pa_w2,256, xatt,256,0, x,256,0,1);

    // ---- LA: relu(bn(conv3x3(x2))) -> xatt[64:128) ----
    la_conv3_k<<<dim3(16,8,32),256,0,stream>>>(x, la_w, p33);
    bnstats_k<float><<<dim3(64,16),256,0,stream>>>(p33,64,0,4096, raw_la);
    bnfin_k<<<1,256,0,stream>>>(raw_la, mv_la, 64, 1.f/131072.f);
    la_post_k<<<32768,256,0,stream>>>(p33, mv_la, xatt);

    // ---- MRA -> xatt[128:192) ----
    mp3_k<<<32768,256,0,stream>>>(x, p33);
    blur_k<<<3872,256,0,stream>>>(p33, xm);
    strips_k<<<3872,256,0,stream>>>(xm, mra_h1, mra_v1, msum);
    shearh_k<<<7568,256,0,stream>>>(xm, sh);
    shconvh_k<<<7568,256,0,stream>>>(sh, mra_h2, sh2);
    shaddh_k<<<3872,256,0,stream>>>(sh2, msum);
    shearv_k<<<7568,256,0,stream>>>(xm, sh);
    shconvv_k<<<7568,256,0,stream>>>(sh, mra_v2, sh2);
    shaddv_k<<<3872,256,0,stream>>>(sh2, msum);
    bnstats_k<float><<<dim3(64,2),256,0,stream>>>(msum,64,0,484, raw_mra);
    bnfin_k<<<1,256,0,stream>>>(raw_mra, mv_mra, 64, 1.f/15488.f);
    mra_gate_k<<<32768,256,0,stream>>>(x, msum, mv_mra, xatt);

    // ---- GA -> xatt[192:256) ----
    pool1_k<<<8192,256,0,stream>>>(x, x4p, idx1);
    pool2_k<<<2048,256,0,stream>>>(x4p, xp, idx2);
    ga_proj_k<<<dim3(8,32),256,0,stream>>>(xp, nullptr, g_p1w, g_p1b, hbuf, 64, 1);
    ga_dw5_k<<<2048,256,0,stream>>>(hbuf, g_c0w, g_c0b, a1);
    ga_dw7_k<<<2048,256,0,stream>>>(a1, g_spw, g_spb, a2);
    ga_proj_k<<<dim3(4,32),256,0,stream>>>(a1, nullptr, g_c1w, g_c1b, a1s, 32, 0);
    ga_proj_k<<<dim3(4,32),256,0,stream>>>(a2, nullptr, g_c2w, g_c2b, a2s, 32, 0);
    ga_agg_k<<<32,256,0,stream>>>(a1s, a2s, agg);
    ga_sq_k<<<64,256,0,stream>>>(agg, g_sqw, g_sqb, sig);
    ga_attn_k<<<dim3(8,32),256,0,stream>>>(a1s, a2s, sig, g_cw, g_cb, attn);
    ga_proj_k<<<dim3(8,32),256,0,stream>>>(hbuf, attn, g_p2w, g_p2b, h2, 64, 0);
    ga_unpool1_k<<<8192,256,0,stream>>>(h2, idx2, xg);
    bnstats_k<float><<<dim3(64,4),256,0,stream>>>(xg,64,0,1024, raw_ga);
    bnfin_k<<<1,256,0,stream>>>(raw_ga, mv_ga, 64, 1.f/32768.f);
    ga_out_k<<<32768,256,0,stream>>>(xg, idx1, mv_ga, xatt);

    // ---- MLP residual: out = x + conv2(relu(bn(conv1(xatt)))) ----
    conv1x1_k<bf16,bf16><<<dim3(4,64,32),256,0,stream>>>(xatt,256,0, nullptr, mlp_w1,256, tbuf,512,0, nullptr,0,0,0);
    bnstats_k<bf16><<<dim3(512,16),256,0,stream>>>(tbuf,512,0,4096, raw_mlp);
    bnfin_k<<<2,256,0,stream>>>(raw_mlp, mv_mlp, 512, 1.f/131072.f);
    conv1x1_k<bf16,float><<<dim3(4,32,32),256,0,stream>>>(tbuf,512,0, mv_mlp, mlp_w2,512, outp,256,0, x,256,0,2);
}

// Round 3
// 1967.508 us; speedup vs baseline: 1.2282x; 1.2282x over previous
//
#include <hip/hip_runtime.h>
#include <hip/hip_bf16.h>
#include <math.h>

typedef __hip_bfloat16 bf16;
typedef __hip_bfloat162 bf162;
typedef __attribute__((ext_vector_type(4))) float f32x4;
typedef __attribute__((ext_vector_type(8))) short s16x8;

static __device__ __forceinline__ float b2f(bf16 v){ return __bfloat162float(v); }
static __device__ __forceinline__ bf16  f2b(float v){ return __float2bfloat16(v); }
static __device__ __forceinline__ float ldf(float v){ return v; }
static __device__ __forceinline__ float ldf(bf16 v){ return __bfloat162float(v); }
static __device__ __forceinline__ float sigm(float v){ return 1.f/(1.f+__expf(-v)); }
static __device__ __forceinline__ short bfbits(float f){ bf16 h = f2b(f); return *reinterpret_cast<short*>(&h); }

#define P_IMG 4096   // 64*64

// ---------------- workspace layout (bytes) ----------------
namespace {
constexpr long long XATT_OFF = 0;
constexpr long long BIG_OFF  = 67108864;
constexpr long long MISC     = 134217728;
constexpr long long XM_OFF   = MISC;                 // f32 (2048,484)
constexpr long long MSUM_OFF = MISC + 3964928;       // f32 (2048,484)
constexpr long long SH_OFF   = MISC + 7929856;       // f32 (2048,946)
constexpr long long SH2_OFF  = MISC + 15679488;      // f32 (2048,946)
constexpr long long X4P_OFF  = MISC + 23429120;      // f32 (32,64,1024)
constexpr long long IDX1_OFF = MISC + 31817728;      // i32 (32,64,1024)
constexpr long long XP_OFF   = MISC + 40206336;      // f32 (32,64,256)
constexpr long long IDX2_OFF = MISC + 42303488;      // i32
constexpr long long HBUF_OFF = MISC + 44400640;      // f32 (32,64,256)
constexpr long long A1_OFF   = MISC + 46497792;
constexpr long long A2_OFF   = MISC + 48594944;
constexpr long long A1S_OFF  = MISC + 50692096;      // f32 (32,32,256)
constexpr long long A2S_OFF  = MISC + 51740672;
constexpr long long AGG_OFF  = MISC + 52789248;      // f32 (32,2,256)
constexpr long long SIG_OFF  = MISC + 52854784;
constexpr long long ATTN_OFF = MISC + 52920320;      // f32 (32,64,256)
constexpr long long H2_OFF   = MISC + 55017472;
constexpr long long XG_OFF   = MISC + 57114624;      // f32 (32,64,1024)
constexpr long long P33_OFF  = 201326592;            // f32 (32,64,4096)
constexpr long long STATS_OFF= 234881024;
constexpr long long WS_NEED  = 234897408;
}

__global__ __launch_bounds__(256) void zero_out_k(float* __restrict__ o, int n){
    int i = blockIdx.x*256 + threadIdx.x;
    if (i < n) o[i] = 0.f;
}

// ======== MFMA 1x1 conv: out[b,o,p] = sum_c f(in[b,c,p]) * W[o,c] ========
// grid (64 px-tiles, Cout/64, 32 b), block 256 = 4 waves (2x2 of 32x32 tiles).
// K staged 64 ch/iter into LDS [px][k] with k-group XOR-swizzle (conflict-lite).
// instats: relu((v-mean)*inv) on input.  epi: 0 plain, 1 aux*sigmoid, 2 aux+acc.
template<typename TIN, typename TOUT>
__global__ __launch_bounds__(256) void convmfma_k(
    const TIN* __restrict__ in, int inCtot, int inOff,
    const float2* __restrict__ instats,
    const float* __restrict__ W, int K,
    TOUT* __restrict__ out, int outCtot, int outOff,
    const float* __restrict__ aux, int auxCtot, int auxOff, int epi)
{
    __shared__ __align__(16) short sB[64*64];
    const int tid = threadIdx.x;
    const int b = blockIdx.z;
    const int Mbase = blockIdx.y * 64;
    const int pxBase = blockIdx.x * 64;
    const int lane = tid & 63, w = tid >> 6;
    const int n16 = lane & 15, q = lane >> 4;
    const int wm = w >> 1, wn = w & 1;

    const TIN* ib = in + ((long)b*inCtot + inOff)*P_IMG + pxBase;
    f32x4 zero = {0.f,0.f,0.f,0.f};
    f32x4 acc[2][2];
    acc[0][0]=zero; acc[0][1]=zero; acc[1][0]=zero; acc[1][1]=zero;

    const int pxp = (tid & 31)*2;
    const int chb = (tid >> 5)*8;

    for (int kb = 0; kb < K; kb += 64){
        __syncthreads();
        #pragma unroll
        for (int i = 0; i < 8; i++){
            int c = chb + i;
            float v0, v1;
            {
                // two adjacent pixels, one vector load
                const TIN* p = ib + (long)(kb + c)*P_IMG + pxp;
                if constexpr (sizeof(TIN) == 2){
                    bf162 t = *(const bf162*)p;
                    v0 = b2f(t.x); v1 = b2f(t.y);
                } else {
                    float2 t = *(const float2*)p;
                    v0 = t.x; v1 = t.y;
                }
            }
            if (instats){
                float2 s = instats[kb + c];
                v0 = (v0 - s.x)*s.y; v0 = v0 > 0.f ? v0 : 0.f;
                v1 = (v1 - s.x)*s.y; v1 = v1 > 0.f ? v1 : 0.f;
            }
            int g0 = ((c>>3) ^ (pxp & 7)) << 3;
            int g1 = ((c>>3) ^ ((pxp+1) & 7)) << 3;
            sB[pxp*64     + g0 + (c&7)] = bfbits(v0);
            sB[(pxp+1)*64 + g1 + (c&7)] = bfbits(v1);
        }
        __syncthreads();
        #pragma unroll
        for (int kk = 0; kk < 2; kk++){
            s16x8 afr[2];
            #pragma unroll
            for (int mt=0; mt<2; mt++){
                int o = Mbase + wm*32 + mt*16 + n16;
                const float* wr = W + (long)o*K + kb + kk*32 + q*8;
                float4 f0 = *(const float4*)wr;
                float4 f1 = *(const float4*)(wr+4);
                s16x8 a;
                a[0]=bfbits(f0.x); a[1]=bfbits(f0.y); a[2]=bfbits(f0.z); a[3]=bfbits(f0.w);
                a[4]=bfbits(f1.x); a[5]=bfbits(f1.y); a[6]=bfbits(f1.z); a[7]=bfbits(f1.w);
                afr[mt] = a;
            }
            s16x8 bfr[2];
            #pragma unroll
            for (int nt=0; nt<2; nt++){
                int n = wn*32 + nt*16 + n16;
                int kgl = kk*4 + q;
                int g = kgl ^ (n & 7);
                bfr[nt] = *(const s16x8*)&sB[n*64 + (g<<3)];
            }
            #pragma unroll
            for (int mt=0; mt<2; mt++)
                #pragma unroll
                for (int nt=0; nt<2; nt++)
                    acc[mt][nt] = __builtin_amdgcn_mfma_f32_16x16x32_bf16(afr[mt], bfr[nt], acc[mt][nt], 0, 0, 0);
        }
    }

    #pragma unroll
    for (int mt=0; mt<2; mt++){
        #pragma unroll
        for (int nt=0; nt<2; nt++){
            int px = pxBase + wn*32 + nt*16 + n16;
            #pragma unroll
            for (int r=0; r<4; r++){
                int o = Mbase + wm*32 + mt*16 + q*4 + r;
                float v = acc[mt][nt][r];
                if (epi == 1){
                    float av = aux[((long)b*auxCtot + auxOff + o)*P_IMG + px];
                    v = av * sigm(v);
                } else if (epi == 2){
                    float av = aux[((long)b*auxCtot + auxOff + o)*P_IMG + px];
                    v = av + v;
                }
                if constexpr (sizeof(TOUT) == 2)
                    out[((long)b*outCtot + outOff + o)*P_IMG + px] = f2b(v);
                else
                    out[((long)b*outCtot + outOff + o)*P_IMG + px] = v;
            }
        }
    }
}

// ============ BN batch-stats ============
template<typename T>
__global__ __launch_bounds__(256) void bnstats_k(const T* __restrict__ in, int Ctot, int cOff, int Pn,
                                                 float* __restrict__ sums)
{
    const int c = blockIdx.x;
    float s=0.f, s2=0.f;
    for (int b=0;b<32;b++){
        const T* qp = in + ((long)b*Ctot + cOff + c)*Pn;
        for (int p = blockIdx.y*256 + threadIdx.x; p < Pn; p += gridDim.y*256){
            float v = ldf(qp[p]);
            s += v; s2 = fmaf(v,v,s2);
        }
    }
    __shared__ float r1[256], r2[256];
    r1[threadIdx.x]=s; r2[threadIdx.x]=s2;
    __syncthreads();
    for (int k=128;k>0;k>>=1){
        if (threadIdx.x<k){ r1[threadIdx.x]+=r1[threadIdx.x+k]; r2[threadIdx.x]+=r2[threadIdx.x+k]; }
        __syncthreads();
    }
    if (threadIdx.x==0){ atomicAdd(&sums[2*c], r1[0]); atomicAdd(&sums[2*c+1], r2[0]); }
}

__global__ __launch_bounds__(256) void bnfin_k(const float* __restrict__ sums, float2* __restrict__ minv,
                                               int C, float invN)
{
    int c = blockIdx.x*256 + threadIdx.x;
    if (c < C){
        float m = sums[2*c]*invN;
        float var = sums[2*c+1]*invN - m*m;
        minv[c] = make_float2(m, 1.f/sqrtf(var + 1e-5f));
    }
}

// ============ LA: 3x3 conv, 64->64, pad 1 ============
__global__ __launch_bounds__(256) void la_conv3_k(const float* __restrict__ x, const float* __restrict__ w,
                                                  float* __restrict__ y)
{
    __shared__ float wsf[64*9*8];
    const int tid = threadIdx.x, og = blockIdx.y, b = blockIdx.z;
    for (int t = tid; t < 64*9*8; t += 256){
        int j = t & 7, ct = t >> 3;
        int c = ct / 9, tap = ct - 9*c;
        wsf[t] = w[((og*8 + j)*64 + c)*9 + tap];
    }
    __syncthreads();
    const int p = blockIdx.x*256 + tid;
    const int h = p >> 6, wc = p & 63;
    float acc[8];
    #pragma unroll
    for (int j=0;j<8;j++) acc[j]=0.f;
    for (int c=0;c<64;c++){
        const float* xb = x + ((long)b*256 + 64 + c)*P_IMG;
        #pragma unroll
        for (int kh=0;kh<3;kh++){
            int hh = h + kh - 1;
            if ((unsigned)hh >= 64u) continue;
            #pragma unroll
            for (int kw=0;kw<3;kw++){
                int ww = wc + kw - 1;
                if ((unsigned)ww >= 64u) continue;
                float v = xb[hh*64 + ww];
                const float* wr = &wsf[(c*9 + kh*3 + kw)*8];
                #pragma unroll
                for (int j=0;j<8;j++) acc[j] = fmaf(v, wr[j], acc[j]);
            }
        }
    }
    #pragma unroll
    for (int j=0;j<8;j++) y[((long)b*64 + og*8 + j)*P_IMG + p] = acc[j];
}

__global__ __launch_bounds__(256) void la_post_k(const float* __restrict__ y, const float2* __restrict__ minv,
                                                 bf16* __restrict__ xatt)
{
    int i = blockIdx.x*256 + threadIdx.x;
    int b = i >> 18, o = (i >> 12) & 63, p = i & 4095;
    float2 st = minv[o];
    float v = (y[i] - st.x)*st.y;
    v = fmaxf(v, 0.f);
    xatt[((long)b*256 + 64 + o)*P_IMG + p] = f2b(v);
}

// ============ MRA ============
__global__ __launch_bounds__(256) void mp3_k(const float* __restrict__ x, float* __restrict__ mp){
    int i = blockIdx.x*256 + threadIdx.x;
    int b = i >> 18, c = (i >> 12) & 63, p = i & 4095;
    int h = p >> 6, wc = p & 63;
    const float* xb = x + ((long)b*256 + 128 + c)*P_IMG;
    float m = -3.4e38f;
    #pragma unroll
    for (int dh=-1; dh<=1; dh++){
        int hh = h+dh; if ((unsigned)hh>=64u) continue;
        #pragma unroll
        for (int dw=-1; dw<=1; dw++){
            int ww = wc+dw; if ((unsigned)ww>=64u) continue;
            m = fmaxf(m, xb[hh*64+ww]);
        }
    }
    mp[i] = m;
}

__global__ __launch_bounds__(256) void blur_k(const float* __restrict__ mp, float* __restrict__ xm){
    int idx = blockIdx.x*256 + threadIdx.x;
    int oj = idx % 22; int t = idx / 22; int oi = t % 22; int bc = t / 22;
    const float* mb = mp + (long)bc * P_IMG;
    const float fw[4] = {1.f,3.f,3.f,1.f};
    float s = 0.f;
    #pragma unroll
    for (int u=0;u<4;u++){
        int r = 3*oi - 1 + u;
        r = r < 0 ? -r : (r > 63 ? 126 - r : r);
        float rs = 0.f;
        #pragma unroll
        for (int v=0; v<4; v++){
            int qq = 3*oj - 1 + v;
            qq = qq < 0 ? -qq : (qq > 63 ? 126 - qq : qq);
            rs = fmaf(fw[v], mb[r*64+qq], rs);
        }
        s = fmaf(fw[u], rs, s);
    }
    xm[idx] = s * (1.f/64.f);
}

__global__ __launch_bounds__(256) void strips_k(const float* __restrict__ xm, const float* __restrict__ wh1,
                                                const float* __restrict__ wv1, float* __restrict__ msum)
{
    int idx = blockIdx.x*256 + threadIdx.x;
    int j = idx % 22; int t = idx / 22; int i = t % 22; int bc = t / 22; int c = bc & 63;
    const float* xb = xm + (long)bc*484;
    float s = 0.f;
    #pragma unroll
    for (int u=0;u<11;u++){
        int ii = i + u - 5; if ((unsigned)ii >= 22u) continue;
        #pragma unroll
        for (int v=0;v<3;v++){
            int jj = j + v - 1; if ((unsigned)jj >= 22u) continue;
            s = fmaf(wh1[c*33 + u*3 + v], xb[ii*22+jj], s);
        }
    }
    #pragma unroll
    for (int u=0;u<3;u++){
        int ii = i + u - 1; if ((unsigned)ii >= 22u) continue;
        #pragma unroll
        for (int v=0;v<11;v++){
            int jj = j + v - 5; if ((unsigned)jj >= 22u) continue;
            s = fmaf(wv1[c*33 + u*11 + v], xb[ii*22+jj], s);
        }
    }
    msum[idx] = s;
}

__global__ __launch_bounds__(256) void shearh_k(const float* __restrict__ xm, float* __restrict__ sh){
    int idx = blockIdx.x*256 + threadIdx.x;
    int j = idx % 43; int t = idx / 43; int i = t % 22; int bc = t / 22;
    int f = i*43 + j; int r = f / 44; int q = f - 44*r;
    sh[idx] = (q < 22) ? xm[(long)bc*484 + r*22 + q] : 0.f;
}

__global__ __launch_bounds__(256) void shconvh_k(const float* __restrict__ sh, const float* __restrict__ w2,
                                                 float* __restrict__ sh2)
{
    int idx = blockIdx.x*256 + threadIdx.x;
    int j = idx % 43; int t = idx / 43; int i = t % 22; int bc = t / 22; int c = bc & 63;
    const float* sb = sh + (long)bc*946;
    float s = 0.f;
    #pragma unroll
    for (int u=0;u<11;u++){
        int ii = i + u - 5; if ((unsigned)ii >= 22u) continue;
        #pragma unroll
        for (int v=0;v<3;v++){
            int jj = j + v - 1; if ((unsigned)jj >= 43u) continue;
            s = fmaf(w2[c*33 + u*3 + v], sb[ii*43+jj], s);
        }
    }
    sh2[idx] = s;
}

__global__ __launch_bounds__(256) void shaddh_k(const float* __restrict__ sh2, float* __restrict__ msum){
    int idx = blockIdx.x*256 + threadIdx.x;
    int j = idx % 22; int t = idx / 22; int i = t % 22; int bc = t / 22;
    int f = i*44 + j; int r = f / 43; int q = f - 43*r;
    msum[idx] += sh2[(long)bc*946 + r*43 + q];
}

__global__ __launch_bounds__(256) void shearv_k(const float* __restrict__ xm, float* __restrict__ sv){
    int idx = blockIdx.x*256 + threadIdx.x;
    int j = idx % 22; int t = idx / 22; int i = t % 43; int bc = t / 43;
    int g = j*43 + i; int r = g / 44; int q = g - 44*r;
    sv[idx] = (q < 22) ? xm[(long)bc*484 + q*22 + r] : 0.f;
}

__global__ __launch_bounds__(256) void shconvv_k(const float* __restrict__ sv, const float* __restrict__ wv2,
                                                 float* __restrict__ sv2)
{
    int idx = blockIdx.x*256 + threadIdx.x;
    int j = idx % 22; int t = idx / 22; int i = t % 43; int bc = t / 43; int c = bc & 63;
    const float* sb = sv + (long)bc*946;
    float s = 0.f;
    #pragma unroll
    for (int u=0;u<3;u++){
        int ii = i + u - 1; if ((unsigned)ii >= 43u) continue;
        #pragma unroll
        for (int v=0;v<11;v++){
            int jj = j + v - 5; if ((unsigned)jj >= 22u) continue;
            s = fmaf(wv2[c*33 + u*11 + v], sb[ii*22+jj], s);
        }
    }
    sv2[idx] = s;
}

__global__ __launch_bounds__(256) void shaddv_k(const float* __restrict__ sv2, float* __restrict__ msum){
    int idx = blockIdx.x*256 + threadIdx.x;
    int xcol = idx % 22; int t = idx / 22; int y = t % 22; int bc = t / 22;
    int g = xcol*44 + y; int r = g / 43; int q = g - 43*r;
    msum[idx] += sv2[(long)bc*946 + q*22 + r];
}

__global__ __launch_bounds__(256) void mra_gate_k(const float* __restrict__ x, const float* __restrict__ msum,
                                                  const float2* __restrict__ minv, bf16* __restrict__ xatt)
{
    int i = blockIdx.x*256 + threadIdx.x;
    int b = i >> 18, c = (i >> 12) & 63, p = i & 4095;
    int h = p >> 6, wcol = p & 63;
    int ri = (h*22) >> 6, ci = (wcol*22) >> 6;
    float g = msum[((long)b*64 + c)*484 + ri*22 + ci];
    float2 st = minv[c];
    g = sigm((g - st.x)*st.y);
    long xi = ((long)b*256 + 128 + c)*P_IMG + p;
    xatt[xi] = f2b(x[xi] * g);
}

// ============ GA ============
__global__ __launch_bounds__(256) void pool1_k(const float* __restrict__ x, float* __restrict__ x4p,
                                               int* __restrict__ idx1)
{
    int i = blockIdx.x*256 + threadIdx.x;
    int b = i >> 16, c = (i >> 10) & 63, s = i & 1023;
    int y = s >> 5, xc = s & 31;
    const float* xb = x + ((long)b*256 + 192 + c)*P_IMG;
    float v00 = xb[(2*y)*64 + 2*xc];
    float v01 = xb[(2*y)*64 + 2*xc + 1];
    float v10 = xb[(2*y+1)*64 + 2*xc];
    float v11 = xb[(2*y+1)*64 + 2*xc + 1];
    float best = v00; int bi = 0;
    if (v01 > best){ best = v01; bi = 1; }
    if (v10 > best){ best = v10; bi = 2; }
    if (v11 > best){ best = v11; bi = 3; }
    x4p[i] = best; idx1[i] = bi;
}

__global__ __launch_bounds__(256) void pool2_k(const float* __restrict__ x4p, float* __restrict__ xp,
                                               int* __restrict__ idx2)
{
    int i = blockIdx.x*256 + threadIdx.x;
    int b = i >> 14, c = (i >> 8) & 63, s = i & 255;
    int y = s >> 4, xc = s & 15;
    const float* xb = x4p + ((long)b*64 + c)*1024;
    float v00 = xb[(2*y)*32 + 2*xc];
    float v01 = xb[(2*y)*32 + 2*xc + 1];
    float v10 = xb[(2*y+1)*32 + 2*xc];
    float v11 = xb[(2*y+1)*32 + 2*xc + 1];
    float best = v00; int bi = 0;
    if (v01 > best){ best = v01; bi = 1; }
    if (v10 > best){ best = v10; bi = 2; }
    if (v11 > best){ best = v11; bi = 3; }
    xp[i] = best; idx2[i] = bi;
}

__global__ __launch_bounds__(256) void ga_proj_k(const float* __restrict__ in, const float* __restrict__ mul,
                                                 const float* __restrict__ w, const float* __restrict__ bias,
                                                 float* __restrict__ out, int Cout, int relu)
{
    int s = threadIdx.x, og = blockIdx.x, b = blockIdx.y;
    float acc[8];
    #pragma unroll
    for (int j=0;j<8;j++) acc[j]=0.f;
    for (int c=0;c<64;c++){
        float v = in[((long)b*64 + c)*256 + s];
        if (mul) v *= mul[((long)b*64 + c)*256 + s];
        #pragma unroll
        for (int j=0;j<8;j++) acc[j] = fmaf(v, w[(og*8 + j)*64 + c], acc[j]);
    }
    #pragma unroll
    for (int j=0;j<8;j++){
        int o = og*8 + j;
        float val = acc[j] + bias[o];
        if (relu) val = fmaxf(val, 0.f);
        out[((long)b*Cout + o)*256 + s] = val;
    }
}

__global__ __launch_bounds__(256) void ga_dw5_k(const float* __restrict__ h, const float* __restrict__ w,
                                                const float* __restrict__ bias, float* __restrict__ a1)
{
    int i = blockIdx.x*256 + threadIdx.x;
    int b = i >> 14, c = (i >> 8) & 63, s = i & 255;
    int y = s >> 4, x = s & 15;
    const float* hb = h + ((long)b*64 + c)*256;
    float acc = bias[c];
    #pragma unroll
    for (int u=0;u<5;u++){
        int yy = y + u - 2; if ((unsigned)yy >= 16u) continue;
        #pragma unroll
        for (int v=0;v<5;v++){
            int xx = x + v - 2; if ((unsigned)xx >= 16u) continue;
            acc = fmaf(w[c*25 + u*5 + v], hb[yy*16 + xx], acc);
        }
    }
    a1[i] = acc;
}

__global__ __launch_bounds__(256) void ga_dw7_k(const float* __restrict__ a1, const float* __restrict__ w,
                                                const float* __restrict__ bias, float* __restrict__ a2)
{
    int i = blockIdx.x*256 + threadIdx.x;
    int b = i >> 14, c = (i >> 8) & 63, s = i & 255;
    int y = s >> 4, x = s & 15;
    const float* ab = a1 + ((long)b*64 + c)*256;
    float acc = bias[c];
    #pragma unroll
    for (int u=0;u<7;u++){
        int yy = y + 3*(u-3); if ((unsigned)yy >= 16u) continue;
        #pragma unroll
        for (int v=0;v<7;v++){
            int xx = x + 3*(v-3); if ((unsigned)xx >= 16u) continue;
            acc = fmaf(w[c*49 + u*7 + v], ab[yy*16 + xx], acc);
        }
    }
    a2[i] = acc;
}

__global__ __launch_bounds__(256) void ga_agg_k(const float* __restrict__ a1s, const float* __restrict__ a2s,
                                                float* __restrict__ agg)
{
    int i = blockIdx.x*256 + threadIdx.x;
    int b = i >> 8, s = i & 255;
    float sum = 0.f, mx = -3.4e38f;
    for (int c=0;c<32;c++){
        float v = a1s[((long)b*32 + c)*256 + s];
        sum += v; mx = fmaxf(mx, v);
    }
    for (int c=0;c<32;c++){
        float v = a2s[((long)b*32 + c)*256 + s];
        sum += v; mx = fmaxf(mx, v);
    }
    agg[((long)b*2 + 0)*256 + s] = sum * (1.f/64.f);
    agg[((long)b*2 + 1)*256 + s] = mx;
}

__global__ __launch_bounds__(256) void ga_sq_k(const float* __restrict__ agg, const float* __restrict__ w,
                                               const float* __restrict__ bias, float* __restrict__ sig)
{
    int i = blockIdx.x*256 + threadIdx.x;
    int b = i >> 9, o = (i >> 8) & 1, s = i & 255;
    int y = s >> 4, x = s & 15;
    float acc = bias[o];
    for (int ic=0; ic<2; ic++){
        const float* ab = agg + ((long)b*2 + ic)*256;
        #pragma unroll
        for (int u=0;u<7;u++){
            int yy = y + u - 3; if ((unsigned)yy >= 16u) continue;
            #pragma unroll
            for (int v=0;v<7;v++){
                int xx = x + v - 3; if ((unsigned)xx >= 16u) continue;
                acc = fmaf(w[((o*2 + ic)*7 + u)*7 + v], ab[yy*16 + xx], acc);
            }
        }
    }
    sig[i] = sigm(acc);
}

__global__ __launch_bounds__(256) void ga_attn_k(const float* __restrict__ a1s, const float* __restrict__ a2s,
                                                 const float* __restrict__ sig, const float* __restrict__ w,
                                                 const float* __restrict__ bias, float* __restrict__ attn)
{
    int s = threadIdx.x, og = blockIdx.x, b = blockIdx.y;
    float s0 = sig[((long)b*2 + 0)*256 + s];
    float s1 = sig[((long)b*2 + 1)*256 + s];
    float acc[8];
    #pragma unroll
    for (int j=0;j<8;j++) acc[j]=0.f;
    for (int c=0;c<32;c++){
        float v = a1s[((long)b*32 + c)*256 + s]*s0 + a2s[((long)b*32 + c)*256 + s]*s1;
        #pragma unroll
        for (int j=0;j<8;j++) acc[j] = fmaf(v, w[(og*8 + j)*32 + c], acc[j]);
    }
    #pragma unroll
    for (int j=0;j<8;j++){
        int o = og*8 + j;
        attn[((long)b*64 + o)*256 + s] = acc[j] + bias[o];
    }
}

__global__ __launch_bounds__(256) void ga_unpool1_k(const float* __restrict__ h2, const int* __restrict__ idx2,
                                                    float* __restrict__ xg)
{
    int i = blockIdx.x*256 + threadIdx.x;
    int b = i >> 16, c = (i >> 10) & 63, s = i & 1023;
    int Y = s >> 5, X = s & 31;
    int slot = ((Y & 1) << 1) | (X & 1);
    long pi = ((long)b*64 + c)*256 + (Y >> 1)*16 + (X >> 1);
    xg[i] = (idx2[pi] == slot) ? h2[pi] : 0.f;
}

__global__ __launch_bounds__(256) void ga_out_k(const float* __restrict__ xg, const int* __restrict__ idx1,
                                                const float2* __restrict__ minv, bf16* __restrict__ xatt)
{
    int i = blockIdx.x*256 + threadIdx.x;
    int b = i >> 18, c = (i >> 12) & 63, p = i & 4095;
    int hh = p >> 6, ww = p & 63;
    int slot = ((hh & 1) << 1) | (ww & 1);
    long pi = ((long)b*64 + c)*1024 + (hh >> 1)*32 + (ww >> 1);
    float v = 0.f;
    if (idx1[pi] == slot){
        float2 st = minv[c];
        v = (xg[pi] - st.x)*st.y;
    }
    xatt[((long)b*256 + 192 + c)*P_IMG + p] = f2b(v);
}

// ============================================================================
extern "C" void kernel_launch(void* const* d_in, const int* in_sizes, int n_in,
                              void* d_out, int out_size, void* d_ws, size_t ws_size,
                              hipStream_t stream)
{
    const float* x      = (const float*)d_in[0];
    const float* pa_w1  = (const float*)d_in[1];
    const float* pa_w2  = (const float*)d_in[2];
    const float* la_w   = (const float*)d_in[3];
    const float* mra_h1 = (const float*)d_in[4];
    const float* mra_v1 = (const float*)d_in[5];
    const float* mra_h2 = (const float*)d_in[6];
    const float* mra_v2 = (const float*)d_in[7];
    const float* g_p1w  = (const float*)d_in[8];
    const float* g_p1b  = (const float*)d_in[9];
    const float* g_c0w  = (const float*)d_in[10];
    const float* g_c0b  = (const float*)d_in[11];
    const float* g_spw  = (const float*)d_in[12];
    const float* g_spb  = (const float*)d_in[13];
    const float* g_c1w  = (const float*)d_in[14];
    const float* g_c1b  = (const float*)d_in[15];
    const float* g_c2w  = (const float*)d_in[16];
    const float* g_c2b  = (const float*)d_in[17];
    const float* g_cw   = (const float*)d_in[18];
    const float* g_cb   = (const float*)d_in[19];
    const float* g_sqw  = (const float*)d_in[20];
    const float* g_sqb  = (const float*)d_in[21];
    const float* g_p2w  = (const float*)d_in[22];
    const float* g_p2b  = (const float*)d_in[23];
    const float* mlp_w1 = (const float*)d_in[24];
    const float* mlp_w2 = (const float*)d_in[25];
    float* outp = (float*)d_out;
    char* ws = (char*)d_ws;

    if (ws_size < (size_t)WS_NEED){
        zero_out_k<<<(out_size + 255)/256, 256, 0, stream>>>(outp, out_size);
        return;
    }

    bf16*  xatt = (bf16*)(ws + XATT_OFF);
    bf16*  tbuf = (bf16*)(ws + BIG_OFF);
    float* xm   = (float*)(ws + XM_OFF);
    float* msum = (float*)(ws + MSUM_OFF);
    float* sh   = (float*)(ws + SH_OFF);
    float* sh2  = (float*)(ws + SH2_OFF);
    float* x4p  = (float*)(ws + X4P_OFF);
    int*   idx1 = (int*)(ws + IDX1_OFF);
    float* xp   = (float*)(ws + XP_OFF);
    int*   idx2 = (int*)(ws + IDX2_OFF);
    float* hbuf = (float*)(ws + HBUF_OFF);
    float* a1   = (float*)(ws + A1_OFF);
    float* a2   = (float*)(ws + A2_OFF);
    float* a1s  = (float*)(ws + A1S_OFF);
    float* a2s  = (float*)(ws + A2S_OFF);
    float* agg  = (float*)(ws + AGG_OFF);
    float* sig  = (float*)(ws + SIG_OFF);
    float* attn = (float*)(ws + ATTN_OFF);
    float* h2   = (float*)(ws + H2_OFF);
    float* xg   = (float*)(ws + XG_OFF);
    float* p33  = (float*)(ws + P33_OFF);
    float* raw  = (float*)(ws + STATS_OFF);
    float*  raw_pa  = raw;
    float*  raw_la  = raw + 512;
    float*  raw_mra = raw + 640;
    float*  raw_ga  = raw + 768;
    float*  raw_mlp = raw + 896;
    float2* mv_pa   = (float2*)(raw + 1920);
    float2* mv_la   = mv_pa + 256;
    float2* mv_mra  = mv_la + 64;
    float2* mv_ga   = mv_mra + 64;
    float2* mv_mlp  = mv_ga + 64;

    hipMemsetAsync(raw, 0, 1920*sizeof(float), stream);

    // ---- PA ----
    convmfma_k<float,bf16><<<dim3(64,4,32),256,0,stream>>>(x,256,0, nullptr, pa_w1,64, tbuf,256,0, nullptr,0,0,0);
    bnstats_k<bf16><<<dim3(256,16),256,0,stream>>>(tbuf,256,0,4096, raw_pa);
    bnfin_k<<<1,256,0,stream>>>(raw_pa, mv_pa, 256, 1.f/131072.f);
    convmfma_k<bf16,bf16><<<dim3(64,1,32),256,0,stream>>>(tbuf,256,0, mv_pa, pa_w2,256, xatt,256,0, x,256,0,1);

    // ---- LA ----
    la_conv3_k<<<dim3(16,8,32),256,0,stream>>>(x, la_w, p33);
    bnstats_k<float><<<dim3(64,16),256,0,stream>>>(p33,64,0,4096, raw_la);
    bnfin_k<<<1,256,0,stream>>>(raw_la, mv_la, 64, 1.f/131072.f);
    la_post_k<<<32768,256,0,stream>>>(p33, mv_la, xatt);

    // ---- MRA ----
    mp3_k<<<32768,256,0,stream>>>(x, p33);
    blur_k<<<3872,256,0,stream>>>(p33, xm);
    strips_k<<<3872,256,0,stream>>>(xm, mra_h1, mra_v1, msum);
    shearh_k<<<7568,256,0,stream>>>(xm, sh);
    shconvh_k<<<7568,256,0,stream>>>(sh, mra_h2, sh2);
    shaddh_k<<<3872,256,0,stream>>>(sh2, msum);
    shearv_k<<<7568,256,0,stream>>>(xm, sh);
    shconvv_k<<<7568,256,0,stream>>>(sh, mra_v2, sh2);
    shaddv_k<<<3872,256,0,stream>>>(sh2, msum);
    bnstats_k<float><<<dim3(64,2),256,0,stream>>>(msum,64,0,484, raw_mra);
    bnfin_k<<<1,256,0,stream>>>(raw_mra, mv_mra, 64, 1.f/15488.f);
    mra_gate_k<<<32768,256,0,stream>>>(x, msum, mv_mra, xatt);

    // ---- GA ----
    pool1_k<<<8192,256,0,stream>>>(x, x4p, idx1);
    pool2_k<<<2048,256,0,stream>>>(x4p, xp, idx2);
    ga_proj_k<<<dim3(8,32),256,0,stream>>>(xp, nullptr, g_p1w, g_p1b, hbuf, 64, 1);
    ga_dw5_k<<<2048,256,0,stream>>>(hbuf, g_c0w, g_c0b, a1);
    ga_dw7_k<<<2048,256,0,stream>>>(a1, g_spw, g_spb, a2);
    ga_proj_k<<<dim3(4,32),256,0,stream>>>(a1, nullptr, g_c1w, g_c1b, a1s, 32, 0);
    ga_proj_k<<<dim3(4,32),256,0,stream>>>(a2, nullptr, g_c2w, g_c2b, a2s, 32, 0);
    ga_agg_k<<<32,256,0,stream>>>(a1s, a2s, agg);
    ga_sq_k<<<64,256,0,stream>>>(agg, g_sqw, g_sqb, sig);
    ga_attn_k<<<dim3(8,32),256,0,stream>>>(a1s, a2s, sig, g_cw, g_cb, attn);
    ga_proj_k<<<dim3(8,32),256,0,stream>>>(hbuf, attn, g_p2w, g_p2b, h2, 64, 0);
    ga_unpool1_k<<<8192,256,0,stream>>>(h2, idx2, xg);
    bnstats_k<float><<<dim3(64,4),256,0,stream>>>(xg,64,0,1024, raw_ga);
    bnfin_k<<<1,256,0,stream>>>(raw_ga, mv_ga, 64, 1.f/32768.f);
    ga_out_k<<<32768,256,0,stream>>>(xg, idx1, mv_ga, xatt);

    // ---- MLP residual ----
    convmfma_k<bf16,bf16><<<dim3(64,8,32),256,0,stream>>>(xatt,256,0, nullptr, mlp_w1,256, tbuf,512,0, nullptr,0,0,0);
    bnstats_k<bf16><<<dim3(512,16),256,0,stream>>>(tbuf,512,0,4096, raw_mlp);
    bnfin_k<<<2,256,0,stream>>>(raw_mlp, mv_mlp, 512, 1.f/131072.f);
    convmfma_k<bf16,float><<<dim3(64,4,32),256,0,stream>>>(tbuf,512,0, mv_mlp, mlp_w2,512, outp,256,0, x,256,0,2);
}